// Round 1
// baseline (963.267 us; speedup 1.0000x reference)
//
#include <hip/hip_runtime.h>
#include <math.h>

#define BB 128
#define SS 2048
#define HH 64
#define CC 4
#define EPSQ 1e-10f

// ---- ws layout ----
// [0, 16KB)        : Q[64][64]  (softmax(base)+EPS)
// [16KB, 16KB+256) : D[64]      (softmax(init)+EPS)
// [32KB, 32KB+1MB) : A[b][t]    per-(b,t) log offset

#define DPP_ADD(s, CTRL)                                                        \
    {                                                                           \
        int _v = __builtin_amdgcn_mov_dpp(__float_as_int(s), CTRL, 0xF, 0xF, true); \
        s += __int_as_float(_v);                                                \
    }

__global__ __launch_bounds__(64) void hmm_setup(const float* __restrict__ base,
                                                const float* __restrict__ init,
                                                float* __restrict__ Q,
                                                float* __restrict__ D) {
    const int i = threadIdx.x;  // 0..63, one wave
    // row-softmax of base_transition_logits (T_TEMP = 1)
    float mx = -INFINITY;
    for (int k = 0; k < HH; ++k) mx = fmaxf(mx, base[i * HH + k]);
    float z = 0.f;
    for (int k = 0; k < HH; ++k) z += expf(base[i * HH + k] - mx);
    float invz = 1.f / z;
    for (int k = 0; k < HH; ++k) Q[i * HH + k] = expf(base[i * HH + k] - mx) * invz + EPSQ;
    // init distribution
    float x = init[i];
    float m2 = x;
    for (int d = 1; d < 64; d <<= 1) m2 = fmaxf(m2, __shfl_xor(m2, d, 64));
    float e = expf(x - m2);
    float zz = e;
    for (int d = 1; d < 64; d <<= 1) zz += __shfl_xor(zz, d, 64);
    D[i] = e / zz + EPSQ;
}

// One workgroup per batch element. 256 threads = 4 waves.
// thread: j = lane>>2 (output state), seg = lane&3 (16 source states each).
// Probability-domain recurrence with per-step state-0 renormalization:
//   U_{t+1}[j] = (sum_i Q[i][j] * U_t[i]) * r_t * E_{t+1}[j],  r_t = 1/U_t[0]
//   alpha[t][j] = A_t + log(U_t[j]),  A_{t+1} = A_t + log(U_t[0])
// Raw U is stored into the alpha output slots; a post-kernel applies A + log().
__global__ __launch_bounds__(256) void hmm_scan(const float* __restrict__ obs,
                                                const float* __restrict__ means,
                                                const float* __restrict__ logvars,
                                                const float* __restrict__ Q,
                                                const float* __restrict__ D,
                                                float* __restrict__ A_ws,
                                                float* __restrict__ out) {
    const int b = blockIdx.x;
    const int lane = threadIdx.x;
    const int seg = lane & 3;
    const int j = lane >> 2;
    const int i0 = seg * 16;

    __shared__ float U[2][HH];
    __shared__ float sc[2][2];    // [buf][0]=r, [buf][1]=log(U[0])
    __shared__ float4 OBS[SS];    // 32 KB: whole obs sequence for this batch

    // preload obs (coalesced float4)
    const float4* obs4 = (const float4*)(obs + (size_t)b * SS * CC);
    for (int t = lane; t < SS; t += 256) OBS[t] = obs4[t];

    // transition fragment: Q[i0+k][j], k=0..15 (one-time, L2/L3-hot)
    float Qr[16];
#pragma unroll
    for (int k = 0; k < 16; ++k) Qr[k] = Q[(i0 + k) * HH + j];

    // emission constants for state j:
    // em = c0 + sum_c a_c*x_c + q_c*x_c^2
    float a_[4], q_[4];
    float c0 = 0.f;
#pragma unroll
    for (int c = 0; c < CC; ++c) {
        float lv = logvars[j * CC + c];
        float var = expf(lv) + 1e-6f;
        float iv = 1.f / var;
        float mu = means[j * CC + c];
        a_[c] = mu * iv;
        q_[c] = -0.5f * iv;
        c0 += logf(6.2831853071795864f * var) + mu * mu * iv;
    }
    c0 = -0.5f * c0;

    float* alpha_b = out + (size_t)b * SS * HH;
    float* A_b = A_ws + (size_t)b * SS;

    __syncthreads();  // OBS ready

    float A = 0.f;  // meaningful in lane 0 only
    // t = 0
    {
        float4 x = OBS[0];
        float em = c0;
        em += a_[0] * x.x + q_[0] * (x.x * x.x);
        em += a_[1] * x.y + q_[1] * (x.y * x.y);
        em += a_[2] * x.z + q_[2] * (x.z * x.z);
        em += a_[3] * x.w + q_[3] * (x.w * x.w);
        float E = expf(em);
        float U0 = D[j] * E;
        if (seg == 0) U[0][j] = U0;
        if (seg == 1) alpha_b[j] = U0;  // raw; post-kernel logs it (A=0)
        if (lane == 0) {
            sc[0][0] = 1.f / U0;
            sc[0][1] = logf(U0);
            A_b[0] = 0.f;
        }
    }

    for (int t = 1; t < SS; ++t) {
        const int cur = (t - 1) & 1;
        const int nxt = t & 1;
        __syncthreads();  // U[cur], sc[cur] visible; U[nxt] free to overwrite

        // emission for (b,t,j) — independent of U reads, overlaps LDS latency
        float4 x = OBS[t];
        float em = c0;
        em += a_[0] * x.x + q_[0] * (x.x * x.x);
        em += a_[1] * x.y + q_[1] * (x.y * x.y);
        em += a_[2] * x.z + q_[2] * (x.z * x.z);
        em += a_[3] * x.w + q_[3] * (x.w * x.w);
        float E = expf(em);

        const float4* Up = (const float4*)&U[cur][i0];
        float4 u0 = Up[0], u1 = Up[1], u2 = Up[2], u3 = Up[3];

        float p0 = Qr[0] * u0.x, p1 = Qr[1] * u0.y, p2 = Qr[2] * u0.z, p3 = Qr[3] * u0.w;
        p0 = fmaf(Qr[4], u1.x, p0);
        p1 = fmaf(Qr[5], u1.y, p1);
        p2 = fmaf(Qr[6], u1.z, p2);
        p3 = fmaf(Qr[7], u1.w, p3);
        p0 = fmaf(Qr[8], u2.x, p0);
        p1 = fmaf(Qr[9], u2.y, p1);
        p2 = fmaf(Qr[10], u2.z, p2);
        p3 = fmaf(Qr[11], u2.w, p3);
        p0 = fmaf(Qr[12], u3.x, p0);
        p1 = fmaf(Qr[13], u3.y, p1);
        p2 = fmaf(Qr[14], u3.z, p2);
        p3 = fmaf(Qr[15], u3.w, p3);
        float s = (p0 + p1) + (p2 + p3);

        // butterfly across the 4 segs (quad_perm DPP) — all 4 lanes get the sum
        DPP_ADD(s, 0xB1);  // [1,0,3,2]
        DPP_ADD(s, 0x4E);  // [2,3,0,1]

        float r = sc[cur][0];
        float Un = s * r * E;

        if (seg == 0) U[nxt][j] = Un;
        if (seg == 1) alpha_b[(size_t)t * HH + j] = Un;  // raw store (16 contig floats/wave)
        if (lane == 0) {
            A += sc[cur][1];
            A_b[t] = A;
            sc[nxt][0] = 1.f / Un;  // lane0 has j==0
            sc[nxt][1] = logf(Un);
        }
    }

    __syncthreads();
    // log-likelihood: ll[b] = A_{S-1} + log(sum_j U_{S-1}[j])
    if (lane < 64) {
        float u = U[(SS - 1) & 1][lane];
        float ssum = u;
        for (int d = 1; d < 64; d <<= 1) ssum += __shfl_xor(ssum, d, 64);
        if (lane == 0) out[(size_t)BB * SS * HH + b] = A + logf(ssum);
    }
}

// alpha[b,t,j] = A[b,t] + log(U_raw[b,t,j]) in-place over d_out
__global__ __launch_bounds__(256) void hmm_post(float* __restrict__ out,
                                                const float* __restrict__ A_ws) {
    const size_t n4 = (size_t)BB * SS * HH / 4;
    const size_t stride = (size_t)gridDim.x * blockDim.x;
    for (size_t i = (size_t)blockIdx.x * blockDim.x + threadIdx.x; i < n4; i += stride) {
        float4 v = ((float4*)out)[i];
        float A = A_ws[i >> 4];  // 16 float4s per (b,t)
        v.x = A + logf(v.x);
        v.y = A + logf(v.y);
        v.z = A + logf(v.z);
        v.w = A + logf(v.w);
        ((float4*)out)[i] = v;
    }
}

extern "C" void kernel_launch(void* const* d_in, const int* in_sizes, int n_in,
                              void* d_out, int out_size, void* d_ws, size_t ws_size,
                              hipStream_t stream) {
    (void)in_sizes; (void)n_in; (void)out_size; (void)ws_size;
    const float* obs     = (const float*)d_in[0];
    const float* base    = (const float*)d_in[1];
    const float* init    = (const float*)d_in[2];
    const float* means   = (const float*)d_in[3];
    const float* logvars = (const float*)d_in[4];
    float* out = (float*)d_out;

    float* Q    = (float*)d_ws;                       // 16 KB
    float* D    = Q + HH * HH;                        // 256 B (at +16 KB)
    float* A_ws = (float*)((char*)d_ws + 32768);      // 1 MB

    hmm_setup<<<1, 64, 0, stream>>>(base, init, Q, D);
    hmm_scan<<<BB, 256, 0, stream>>>(obs, means, logvars, Q, D, A_ws, out);
    hmm_post<<<2048, 256, 0, stream>>>(out, A_ws);
}

// Round 2
// 881.815 us; speedup vs baseline: 1.0924x; 1.0924x over previous
//
#include <hip/hip_runtime.h>
#include <math.h>

#define BB 128
#define SS 2048
#define HH 64
#define CC 4
#define EPSQ 1e-10f
#define NT ((size_t)BB * SS * HH)

// ---- ws layout ----
// 0      : Qt[64][64]   Qt[j][i] = softmax(base)[i][j] + EPS   (16 KB)
// 16384  : D[64]        softmax(init)+EPS                      (256 B)
// 16640  : cstA[64]     float4 (mu/var per channel)            (1 KB)
// 17664  : cstQ[64]     float4 (-0.5/var per channel)          (1 KB)
// 18688  : cstC[64]     float  (const term)                    (256 B)
// 32768  : A_ws[128][2048] per-(b,t) log offset                (1 MB)

__global__ __launch_bounds__(64) void hmm_setup(const float* __restrict__ base,
                                                const float* __restrict__ init,
                                                const float* __restrict__ means,
                                                const float* __restrict__ logvars,
                                                float* __restrict__ Qt,
                                                float* __restrict__ D,
                                                float4* __restrict__ cstA,
                                                float4* __restrict__ cstQ,
                                                float* __restrict__ cstC) {
    const int i = threadIdx.x;  // 0..63
    // row-softmax of base_transition_logits, stored TRANSPOSED (+EPS)
    float mx = -INFINITY;
    for (int k = 0; k < HH; ++k) mx = fmaxf(mx, base[i * HH + k]);
    float z = 0.f;
    for (int k = 0; k < HH; ++k) z += expf(base[i * HH + k] - mx);
    float invz = 1.f / z;
    for (int k = 0; k < HH; ++k) Qt[k * HH + i] = expf(base[i * HH + k] - mx) * invz + EPSQ;
    // init distribution
    float x = init[i];
    float m2 = x;
    for (int d = 1; d < 64; d <<= 1) m2 = fmaxf(m2, __shfl_xor(m2, d, 64));
    float e = expf(x - m2);
    float zz = e;
    for (int d = 1; d < 64; d <<= 1) zz += __shfl_xor(zz, d, 64);
    D[i] = e / zz + EPSQ;
    // emission constants for state i
    float av[4], qv[4];
    float c0 = 0.f;
    for (int c = 0; c < CC; ++c) {
        float var = expf(logvars[i * CC + c]) + 1e-6f;
        float iv = 1.f / var;
        float mu = means[i * CC + c];
        av[c] = mu * iv;
        qv[c] = -0.5f * iv;
        c0 += logf(6.2831853071795864f * var) + mu * mu * iv;
    }
    cstA[i] = make_float4(av[0], av[1], av[2], av[3]);
    cstQ[i] = make_float4(qv[0], qv[1], qv[2], qv[3]);
    cstC[i] = -0.5f * c0;
}

// E[b,t,j] = exp(em[b,t,j]) written into the alpha slots of d_out.
__global__ __launch_bounds__(256) void hmm_pre(const float4* __restrict__ obs4,
                                               const float4* __restrict__ cstA,
                                               const float4* __restrict__ cstQ,
                                               const float* __restrict__ cstC,
                                               float* __restrict__ E) {
    const size_t stride = (size_t)gridDim.x * 256;
    for (size_t idx = (size_t)blockIdx.x * 256 + threadIdx.x; idx < NT; idx += stride) {
        const int j = (int)(idx & 63);
        const size_t bt = idx >> 6;
        float4 x = obs4[bt];
        float4 a = cstA[j];
        float4 q = cstQ[j];
        float em = cstC[j];
        em += (a.x + q.x * x.x) * x.x;
        em += (a.y + q.y * x.y) * x.y;
        em += (a.z + q.z * x.z) * x.z;
        em += (a.w + q.w * x.w) * x.w;
        E[idx] = __expf(em);
    }
}

// One wave (64 lanes) per batch. Lane j owns U[j]. No barriers (wave-synchronous;
// DS ops within a wave complete in order). Per step:
//   U_t[j] = (sum_i Qt[j][i] * U_{t-1}[i]) * g_t * E_t[j]
// with delayed renorm g_t = rcp(U_{t-1}[0]) computed at the end of step t-1
// (off the critical path). alpha[t][j] = A_t + log(U_t[j]), A_t = A_{t-1} - log(g_t).
// Raw U overwrites the E slot in d_out; post-kernel applies A + log().
template <int SLOT, int P>
__device__ __forceinline__ void hmm_step(int t, int j, float& u, float& g, float& A,
                                         float (&Epf)[8], const float4 (&Qr)[16],
                                         float (&Ubuf)[2][HH],
                                         float* __restrict__ Eb,
                                         float* __restrict__ A_b) {
    Ubuf[P][j] = u;  // ds_write_b32; same-wave DS in-order vs. following reads
    const float E = Epf[SLOT];
    const int tp = (t + 8 <= SS - 1) ? t + 8 : SS - 1;
    const float Enew = Eb[(size_t)tp * HH + j];  // prefetch (dummy near the end)
    const float gE = g * E;                      // g ready from previous step
    const float4* Up = (const float4*)Ubuf[P];
    float ax = 0.f, ay = 0.f, az = 0.f, aw = 0.f;
#pragma unroll
    for (int k = 0; k < 16; ++k) {
        float4 uu = Up[k];   // broadcast ds_read_b128 (all lanes same addr)
        float4 qq = Qr[k];
        ax = fmaf(qq.x, uu.x, ax);
        ay = fmaf(qq.y, uu.y, ay);
        az = fmaf(qq.z, uu.z, az);
        aw = fmaf(qq.w, uu.w, aw);
    }
    const float s = (ax + ay) + (az + aw);
    const float un = s * gE;
    Eb[(size_t)t * HH + j] = un;  // raw U over the E slot
    A -= logf(g);                 // exact consistency with the applied scale
    if (j == 0) A_b[t] = A;
    // next step's scale: off the critical path of step t+1's dot
    g = __builtin_amdgcn_rcpf(__int_as_float(
        __builtin_amdgcn_readfirstlane(__float_as_int(un))));
    Epf[SLOT] = Enew;
    u = un;
}

__global__ __launch_bounds__(64, 1) void hmm_scan(const float* __restrict__ Qt,
                                                  const float* __restrict__ D,
                                                  float* __restrict__ A_ws,
                                                  float* __restrict__ out) {
    const int b = blockIdx.x;
    const int j = threadIdx.x;  // 0..63 = state
    __shared__ float Ubuf[2][HH];

    float* Eb = out + (size_t)b * SS * HH;  // E in, raw U out
    float* A_b = A_ws + (size_t)b * SS;

    // transition column j (row of Qt) into registers: 16 float4 = 64 VGPRs
    float4 Qr[16];
    const float4* qrow = (const float4*)(Qt + (size_t)j * HH);
#pragma unroll
    for (int k = 0; k < 16; ++k) Qr[k] = qrow[k];

    // t = 0
    float u = D[j] * Eb[j];
    Eb[j] = u;
    float A = 0.f;
    if (j == 0) A_b[0] = 0.f;
    float g = __builtin_amdgcn_rcpf(__int_as_float(
        __builtin_amdgcn_readfirstlane(__float_as_int(u))));

    // prefetch E for t = 1..8 into ring slots (t & 7)
    float Epf[8];
#pragma unroll
    for (int k = 1; k <= 8; ++k) Epf[k & 7] = Eb[(size_t)k * HH + j];

    // prologue: t = 1..7  (slot = t&7, parity = t&1)
    hmm_step<1, 1>(1, j, u, g, A, Epf, Qr, Ubuf, Eb, A_b);
    hmm_step<2, 0>(2, j, u, g, A, Epf, Qr, Ubuf, Eb, A_b);
    hmm_step<3, 1>(3, j, u, g, A, Epf, Qr, Ubuf, Eb, A_b);
    hmm_step<4, 0>(4, j, u, g, A, Epf, Qr, Ubuf, Eb, A_b);
    hmm_step<5, 1>(5, j, u, g, A, Epf, Qr, Ubuf, Eb, A_b);
    hmm_step<6, 0>(6, j, u, g, A, Epf, Qr, Ubuf, Eb, A_b);
    hmm_step<7, 1>(7, j, u, g, A, Epf, Qr, Ubuf, Eb, A_b);

    // main: t = 8..2047 in groups of 8 (t0 even -> parity = o&1, slot = o)
    for (int t0 = 8; t0 < SS; t0 += 8) {
        hmm_step<0, 0>(t0 + 0, j, u, g, A, Epf, Qr, Ubuf, Eb, A_b);
        hmm_step<1, 1>(t0 + 1, j, u, g, A, Epf, Qr, Ubuf, Eb, A_b);
        hmm_step<2, 0>(t0 + 2, j, u, g, A, Epf, Qr, Ubuf, Eb, A_b);
        hmm_step<3, 1>(t0 + 3, j, u, g, A, Epf, Qr, Ubuf, Eb, A_b);
        hmm_step<4, 0>(t0 + 4, j, u, g, A, Epf, Qr, Ubuf, Eb, A_b);
        hmm_step<5, 1>(t0 + 5, j, u, g, A, Epf, Qr, Ubuf, Eb, A_b);
        hmm_step<6, 0>(t0 + 6, j, u, g, A, Epf, Qr, Ubuf, Eb, A_b);
        hmm_step<7, 1>(t0 + 7, j, u, g, A, Epf, Qr, Ubuf, Eb, A_b);
    }

    // log-likelihood: ll[b] = A_{S-1} + log(sum_j U_{S-1}[j])
    float ssum = u;
    for (int d = 1; d < 64; d <<= 1) ssum += __shfl_xor(ssum, d, 64);
    if (j == 0) out[NT + b] = A + logf(ssum);
}

// alpha[b,t,j] = A[b,t] + log(U_raw[b,t,j]) in-place over d_out
__global__ __launch_bounds__(256) void hmm_post(float* __restrict__ out,
                                                const float* __restrict__ A_ws) {
    const size_t n4 = NT / 4;
    const size_t stride = (size_t)gridDim.x * blockDim.x;
    for (size_t i = (size_t)blockIdx.x * blockDim.x + threadIdx.x; i < n4; i += stride) {
        float4 v = ((float4*)out)[i];
        float A = A_ws[i >> 4];  // 16 float4s per (b,t)
        v.x = A + logf(v.x);
        v.y = A + logf(v.y);
        v.z = A + logf(v.z);
        v.w = A + logf(v.w);
        ((float4*)out)[i] = v;
    }
}

extern "C" void kernel_launch(void* const* d_in, const int* in_sizes, int n_in,
                              void* d_out, int out_size, void* d_ws, size_t ws_size,
                              hipStream_t stream) {
    (void)in_sizes; (void)n_in; (void)out_size; (void)ws_size;
    const float* obs     = (const float*)d_in[0];
    const float* base    = (const float*)d_in[1];
    const float* init    = (const float*)d_in[2];
    const float* means   = (const float*)d_in[3];
    const float* logvars = (const float*)d_in[4];
    float* out = (float*)d_out;

    float*  Qt   = (float*)d_ws;                           // 16 KB
    float*  D    = (float*)((char*)d_ws + 16384);          // 256 B
    float4* cstA = (float4*)((char*)d_ws + 16640);         // 1 KB
    float4* cstQ = (float4*)((char*)d_ws + 17664);         // 1 KB
    float*  cstC = (float*)((char*)d_ws + 18688);          // 256 B
    float*  A_ws = (float*)((char*)d_ws + 32768);          // 1 MB

    hmm_setup<<<1, 64, 0, stream>>>(base, init, means, logvars, Qt, D, cstA, cstQ, cstC);
    hmm_pre<<<8192, 256, 0, stream>>>((const float4*)obs, cstA, cstQ, cstC, out);
    hmm_scan<<<BB, 64, 0, stream>>>(Qt, D, A_ws, out);
    hmm_post<<<2048, 256, 0, stream>>>(out, A_ws);
}

// Round 3
// 837.942 us; speedup vs baseline: 1.1496x; 1.0524x over previous
//
#include <hip/hip_runtime.h>
#include <math.h>

#define BB 128
#define SS 2048
#define HH 64
#define CC 4
#define EPSQ 1e-10f
#define NT ((size_t)BB * SS * HH)

// ---- ws layout ----
// 0      : Qt[64][64]   Qt[j][i] = softmax(base)[i][j] + EPS   (16 KB)
// 16384  : D[64]        softmax(init)+EPS                      (256 B)
// 32768  : A_ws[128][2048] per-(b,t) log offset                (1 MB)

__global__ __launch_bounds__(64) void hmm_setup(const float* __restrict__ base,
                                                const float* __restrict__ init,
                                                float* __restrict__ Qt,
                                                float* __restrict__ D) {
    const int i = threadIdx.x;  // 0..63
    // row-softmax of base_transition_logits, stored TRANSPOSED (+EPS)
    float mx = -INFINITY;
    for (int k = 0; k < HH; ++k) mx = fmaxf(mx, base[i * HH + k]);
    float z = 0.f;
    for (int k = 0; k < HH; ++k) z += expf(base[i * HH + k] - mx);
    float invz = 1.f / z;
    for (int k = 0; k < HH; ++k) Qt[k * HH + i] = expf(base[i * HH + k] - mx) * invz + EPSQ;
    // init distribution
    float x = init[i];
    float m2 = x;
    for (int d = 1; d < 64; d <<= 1) m2 = fmaxf(m2, __shfl_xor(m2, d, 64));
    float e = expf(x - m2);
    float zz = e;
    for (int d = 1; d < 64; d <<= 1) zz += __shfl_xor(zz, d, 64);
    D[i] = e / zz + EPSQ;
}

// em(x) for state j given per-state constants: c0 + sum_c (a_c + q_c*x_c)*x_c
__device__ __forceinline__ float emv(const float4 x, const float4 a, const float4 q, float c0) {
    float em = c0;
    em = fmaf(fmaf(q.x, x.x, a.x), x.x, em);
    em = fmaf(fmaf(q.y, x.y, a.y), x.y, em);
    em = fmaf(fmaf(q.z, x.z, a.z), x.z, em);
    em = fmaf(fmaf(q.w, x.w, a.w), x.w, em);
    return em;
}

// One wave (64 lanes) per batch. Lane j owns U[j]. No barriers (single-wave,
// DS unit processes the wave's LDS ops in order). Per step:
//   U_t[j] = (sum_i Qt[j][i] * U_{t-1}[i]) * g_t * E_t[j]
// g_t = rcp(U_{t-1}[0]) and E_t = exp(em_t) are both produced at the END of
// step t-1 (off the critical path). NO global loads in the loop: obs lives in
// LDS, emissions computed in-register one step ahead. Stores are fire-and-forget.
// alpha[t][j] = A_t + log(U_t[j]); A_t = A_{t-1} - log(g_t). Raw U goes to the
// alpha slots of d_out; a post-kernel applies A + log().
template <int P>
__device__ __forceinline__ void hmm_step(int t, int j, float& u, float& gE, float& gcur,
                                         float& A, const float4 (&Qr)[16],
                                         float (&Ubuf)[2][HH], const float4* OBS,
                                         const float4 ea, const float4 eq, float ec,
                                         float* __restrict__ Ub, float* __restrict__ A_b) {
    Ubuf[P][j] = u;  // ds_write_b32; in-order DS => later reads see it
    const float4* Up = (const float4*)Ubuf[P];
    float ax, ay, az, aw;
    {
        float4 uu = Up[0];  // broadcast ds_read_b128 (all lanes same addr)
        float4 qq = Qr[0];
        ax = uu.x * qq.x; ay = uu.y * qq.y; az = uu.z * qq.z; aw = uu.w * qq.w;
    }
#pragma unroll
    for (int k = 1; k < 16; ++k) {
        float4 uu = Up[k];
        float4 qq = Qr[k];
        ax = fmaf(qq.x, uu.x, ax);
        ay = fmaf(qq.y, uu.y, ay);
        az = fmaf(qq.z, uu.z, az);
        aw = fmaf(qq.w, uu.w, aw);
    }
    const int tn = (t < SS - 1) ? t + 1 : SS - 1;
    const float4 xn = OBS[tn];  // broadcast read; consumer is late (E for t+1)

    const float s = (ax + ay) + (az + aw);
    const float un = s * gE;                 // gE ready since end of step t-1
    Ub[(size_t)t * HH + j] = un;             // raw U -> alpha slot (coalesced 256B)
    A -= __logf(gcur);
    if (j == 0) A_b[t] = A;
    // next step's scale+emission: off the critical path of step t+1's dot
    const float gn = __builtin_amdgcn_rcpf(__int_as_float(
        __builtin_amdgcn_readfirstlane(__float_as_int(un))));
    const float En = __expf(emv(xn, ea, eq, ec));
    gcur = gn;
    gE = gn * En;
    u = un;
}

__global__ __launch_bounds__(64, 1) void hmm_scan(const float* __restrict__ obs,
                                                  const float* __restrict__ means,
                                                  const float* __restrict__ logvars,
                                                  const float* __restrict__ Qt,
                                                  const float* __restrict__ D,
                                                  float* __restrict__ A_ws,
                                                  float* __restrict__ out) {
    const int b = blockIdx.x;
    const int j = threadIdx.x;  // 0..63 = state
    __shared__ float4 OBS[SS];     // 32 KB: whole obs sequence for this batch
    __shared__ float Ubuf[2][HH];  // 512 B

    // stage obs (coalesced float4; wave-synchronous, no barrier needed)
    const float4* obs4 = (const float4*)obs + (size_t)b * SS;
#pragma unroll 8
    for (int t = j; t < SS; t += 64) OBS[t] = obs4[t];

    // transition column j (row of Qt): 16 float4 = 64 VGPRs
    float4 Qr[16];
    const float4* qrow = (const float4*)(Qt + (size_t)j * HH);
#pragma unroll
    for (int k = 0; k < 16; ++k) Qr[k] = qrow[k];

    // emission constants for state j
    const float4 mu = ((const float4*)means)[j];
    const float4 lv = ((const float4*)logvars)[j];
    float4 ea, eq;
    float ec = 0.f;
    {
        float v0 = __expf(lv.x) + 1e-6f, v1 = __expf(lv.y) + 1e-6f;
        float v2 = __expf(lv.z) + 1e-6f, v3 = __expf(lv.w) + 1e-6f;
        float i0 = 1.f / v0, i1 = 1.f / v1, i2 = 1.f / v2, i3 = 1.f / v3;
        ea = make_float4(mu.x * i0, mu.y * i1, mu.z * i2, mu.w * i3);
        eq = make_float4(-0.5f * i0, -0.5f * i1, -0.5f * i2, -0.5f * i3);
        ec += logf(6.2831853071795864f * v0) + mu.x * mu.x * i0;
        ec += logf(6.2831853071795864f * v1) + mu.y * mu.y * i1;
        ec += logf(6.2831853071795864f * v2) + mu.z * mu.z * i2;
        ec += logf(6.2831853071795864f * v3) + mu.w * mu.w * i3;
        ec = -0.5f * ec;
    }

    float* Ub = out + (size_t)b * SS * HH;  // raw U into alpha slots
    float* A_b = A_ws + (size_t)b * SS;

    // t = 0
    float u = D[j] * __expf(emv(OBS[0], ea, eq, ec));
    Ub[j] = u;
    float A = 0.f;
    if (j == 0) A_b[0] = 0.f;
    float gcur = __builtin_amdgcn_rcpf(__int_as_float(
        __builtin_amdgcn_readfirstlane(__float_as_int(u))));
    float gE = gcur * __expf(emv(OBS[1], ea, eq, ec));

    // t = 1..2046 in pairs, then the final odd step
    for (int t = 1; t + 1 < SS; t += 2) {
        hmm_step<1>(t, j, u, gE, gcur, A, Qr, Ubuf, OBS, ea, eq, ec, Ub, A_b);
        hmm_step<0>(t + 1, j, u, gE, gcur, A, Qr, Ubuf, OBS, ea, eq, ec, Ub, A_b);
    }
    hmm_step<1>(SS - 1, j, u, gE, gcur, A, Qr, Ubuf, OBS, ea, eq, ec, Ub, A_b);

    // log-likelihood: ll[b] = A_{S-1} + log(sum_j U_{S-1}[j])
    float ssum = u;
    for (int d = 1; d < 64; d <<= 1) ssum += __shfl_xor(ssum, d, 64);
    if (j == 0) out[NT + b] = A + __logf(ssum);
}

// alpha[b,t,j] = A[b,t] + log(U_raw[b,t,j]) in-place over d_out
__global__ __launch_bounds__(256) void hmm_post(float* __restrict__ out,
                                                const float* __restrict__ A_ws) {
    const size_t n4 = NT / 4;
    const size_t stride = (size_t)gridDim.x * blockDim.x;
    for (size_t i = (size_t)blockIdx.x * blockDim.x + threadIdx.x; i < n4; i += stride) {
        float4 v = ((float4*)out)[i];
        float A = A_ws[i >> 4];  // 16 float4s per (b,t)
        v.x = A + logf(v.x);
        v.y = A + logf(v.y);
        v.z = A + logf(v.z);
        v.w = A + logf(v.w);
        ((float4*)out)[i] = v;
    }
}

extern "C" void kernel_launch(void* const* d_in, const int* in_sizes, int n_in,
                              void* d_out, int out_size, void* d_ws, size_t ws_size,
                              hipStream_t stream) {
    (void)in_sizes; (void)n_in; (void)out_size; (void)ws_size;
    const float* obs     = (const float*)d_in[0];
    const float* base    = (const float*)d_in[1];
    const float* init    = (const float*)d_in[2];
    const float* means   = (const float*)d_in[3];
    const float* logvars = (const float*)d_in[4];
    float* out = (float*)d_out;

    float* Qt   = (float*)d_ws;                       // 16 KB
    float* D    = (float*)((char*)d_ws + 16384);      // 256 B
    float* A_ws = (float*)((char*)d_ws + 32768);      // 1 MB

    hmm_setup<<<1, 64, 0, stream>>>(base, init, Qt, D);
    hmm_scan<<<BB, 64, 0, stream>>>(obs, means, logvars, Qt, D, A_ws, out);
    hmm_post<<<2048, 256, 0, stream>>>(out, A_ws);
}

// Round 4
// 701.608 us; speedup vs baseline: 1.3729x; 1.1943x over previous
//
#include <hip/hip_runtime.h>
#include <math.h>

#define BB 128
#define SS 2048
#define HH 64
#define CC 4
#define EPSQ 1e-10f
#define NT ((size_t)BB * SS * HH)

// ---- ws layout ----
// 0      : Qt[64][64]   Qt[j][i] = softmax(base)[i][j] + EPS   (16 KB)
// 16384  : D[64]        softmax(init)+EPS                      (256 B)
// 32768  : A_ws[128][2048] per-(b,t) log offset                (1 MB)

__global__ __launch_bounds__(64) void hmm_setup(const float* __restrict__ base,
                                                const float* __restrict__ init,
                                                float* __restrict__ Qt,
                                                float* __restrict__ D) {
    const int i = threadIdx.x;  // 0..63
    // row-softmax of base_transition_logits, stored TRANSPOSED (+EPS)
    float mx = -INFINITY;
    for (int k = 0; k < HH; ++k) mx = fmaxf(mx, base[i * HH + k]);
    float z = 0.f;
    for (int k = 0; k < HH; ++k) z += expf(base[i * HH + k] - mx);
    float invz = 1.f / z;
    for (int k = 0; k < HH; ++k) Qt[k * HH + i] = expf(base[i * HH + k] - mx) * invz + EPSQ;
    // init distribution
    float x = init[i];
    float m2 = x;
    for (int d = 1; d < 64; d <<= 1) m2 = fmaxf(m2, __shfl_xor(m2, d, 64));
    float e = expf(x - m2);
    float zz = e;
    for (int d = 1; d < 64; d <<= 1) zz += __shfl_xor(zz, d, 64);
    D[i] = e / zz + EPSQ;
}

// em(x) for state j: c0 + sum_c (a_c + q_c*x_c)*x_c
__device__ __forceinline__ float emv(const float4 x, const float4 a, const float4 q, float c0) {
    float em = c0;
    em = fmaf(fmaf(q.x, x.x, a.x), x.x, em);
    em = fmaf(fmaf(q.y, x.y, a.y), x.y, em);
    em = fmaf(fmaf(q.z, x.z, a.z), x.z, em);
    em = fmaf(fmaf(q.w, x.w, a.w), x.w, em);
    return em;
}

#define RL(i) __int_as_float(__builtin_amdgcn_readlane(__float_as_int(u), (i)))

// One wave per batch, lane j owns U[j]. The all-to-all broadcast of U is done
// with v_readlane (VGPR -> SGPR) + FMA with SGPR operand: no LDS, no memory
// latency on the critical path. Per step:
//   U_t[j] = (sum_i Qt[j][i] * U_{t-1}[i]) * g_t * E_t[j]
// g_t = rcp(U_{t-1}[0]) and E_t = exp(em_t) are produced at the END of step
// t-1 (off the critical path). alpha[t][j] = A_t + log(U_t[j]), A_t = A_{t-1}
// - log(g_t). Raw U goes to the alpha slots of d_out; post applies A + log().
// A values are captured per-lane (lane t&63 at step t) and flushed as one
// coalesced store every 64 steps.
__global__ __launch_bounds__(64, 1) void hmm_scan(const float* __restrict__ obs,
                                                  const float* __restrict__ means,
                                                  const float* __restrict__ logvars,
                                                  const float* __restrict__ Qt,
                                                  const float* __restrict__ D,
                                                  float* __restrict__ A_ws,
                                                  float* __restrict__ out) {
    const int b = blockIdx.x;
    const int j = threadIdx.x;  // 0..63 = state
    __shared__ float4 OBS[SS];  // 32 KB: whole obs sequence for this batch

    // stage obs (coalesced float4; single wave => no barrier)
    const float4* obs4 = (const float4*)obs + (size_t)b * SS;
#pragma unroll 8
    for (int t = j; t < SS; t += 64) OBS[t] = obs4[t];

    // transition column j (row of Qt) into 64 scalar VGPRs
    float qr[64];
    const float4* qrow = (const float4*)(Qt + (size_t)j * HH);
#pragma unroll
    for (int k = 0; k < 16; ++k) {
        float4 v = qrow[k];
        qr[4 * k + 0] = v.x;
        qr[4 * k + 1] = v.y;
        qr[4 * k + 2] = v.z;
        qr[4 * k + 3] = v.w;
    }

    // emission constants for state j
    const float4 mu = ((const float4*)means)[j];
    const float4 lv = ((const float4*)logvars)[j];
    float4 ea, eq;
    float ec = 0.f;
    {
        float v0 = __expf(lv.x) + 1e-6f, v1 = __expf(lv.y) + 1e-6f;
        float v2 = __expf(lv.z) + 1e-6f, v3 = __expf(lv.w) + 1e-6f;
        float i0 = 1.f / v0, i1 = 1.f / v1, i2 = 1.f / v2, i3 = 1.f / v3;
        ea = make_float4(mu.x * i0, mu.y * i1, mu.z * i2, mu.w * i3);
        eq = make_float4(-0.5f * i0, -0.5f * i1, -0.5f * i2, -0.5f * i3);
        ec += logf(6.2831853071795864f * v0) + mu.x * mu.x * i0;
        ec += logf(6.2831853071795864f * v1) + mu.y * mu.y * i1;
        ec += logf(6.2831853071795864f * v2) + mu.z * mu.z * i2;
        ec += logf(6.2831853071795864f * v3) + mu.w * mu.w * i3;
        ec = -0.5f * ec;
    }

    float* Ub = out + (size_t)b * SS * HH;  // raw U into alpha slots
    float* A_b = A_ws + (size_t)b * SS;

    // t = 0
    float u = D[j] * __expf(emv(OBS[0], ea, eq, ec));
    Ub[j] = u;
    float A = 0.f;
    float Asave = 0.f;  // lane 0 holds A_b[0] = 0
    float gcur = __builtin_amdgcn_rcpf(__int_as_float(
        __builtin_amdgcn_readfirstlane(__float_as_int(u))));
    float gE = gcur * __expf(emv(OBS[1], ea, eq, ec));

#pragma unroll 2
    for (int t = 1; t < SS; ++t) {
        // prefetch next obs early (LDS broadcast; consumer is late)
        const int tn = (t < SS - 1) ? t + 1 : SS - 1;
        const float4 xn = OBS[tn];

        // dot: s = sum_i qr[i] * U[i], U[i] broadcast via readlane (no memory)
        float a0 = qr[0] * RL(0), a1 = qr[1] * RL(1);
        float a2 = qr[2] * RL(2), a3 = qr[3] * RL(3);
#pragma unroll
        for (int i = 4; i < 64; i += 4) {
            a0 = fmaf(qr[i + 0], RL(i + 0), a0);
            a1 = fmaf(qr[i + 1], RL(i + 1), a1);
            a2 = fmaf(qr[i + 2], RL(i + 2), a2);
            a3 = fmaf(qr[i + 3], RL(i + 3), a3);
        }
        const float s = (a0 + a1) + (a2 + a3);
        const float un = s * gE;  // gE ready since end of step t-1
        Ub[(size_t)t * HH + j] = un;  // fire-and-forget, coalesced 256 B

        // A bookkeeping: uniform value, captured by lane (t&63), flushed /64
        A -= __logf(gcur);
        Asave = (j == (t & 63)) ? A : Asave;
        if ((t & 63) == 63) A_b[t - 63 + j] = Asave;  // uniform branch, coalesced

        // next step's scale & emission (off the critical path of t+1's dot)
        gcur = __builtin_amdgcn_rcpf(__int_as_float(
            __builtin_amdgcn_readfirstlane(__float_as_int(un))));
        gE = gcur * __expf(emv(xn, ea, eq, ec));
        u = un;
    }

    // log-likelihood: ll[b] = A_{S-1} + log(sum_j U_{S-1}[j])
    float ssum = u;
    for (int d = 1; d < 64; d <<= 1) ssum += __shfl_xor(ssum, d, 64);
    if (j == 0) out[NT + b] = A + __logf(ssum);
}

// alpha[b,t,j] = A[b,t] + log(U_raw[b,t,j]) in-place over d_out
__global__ __launch_bounds__(256) void hmm_post(float* __restrict__ out,
                                                const float* __restrict__ A_ws) {
    const size_t n4 = NT / 4;
    const size_t stride = (size_t)gridDim.x * blockDim.x;
    for (size_t i = (size_t)blockIdx.x * blockDim.x + threadIdx.x; i < n4; i += stride) {
        float4 v = ((float4*)out)[i];
        float A = A_ws[i >> 4];  // 16 float4s per (b,t)
        v.x = A + logf(v.x);
        v.y = A + logf(v.y);
        v.z = A + logf(v.z);
        v.w = A + logf(v.w);
        ((float4*)out)[i] = v;
    }
}

extern "C" void kernel_launch(void* const* d_in, const int* in_sizes, int n_in,
                              void* d_out, int out_size, void* d_ws, size_t ws_size,
                              hipStream_t stream) {
    (void)in_sizes; (void)n_in; (void)out_size; (void)ws_size;
    const float* obs     = (const float*)d_in[0];
    const float* base    = (const float*)d_in[1];
    const float* init    = (const float*)d_in[2];
    const float* means   = (const float*)d_in[3];
    const float* logvars = (const float*)d_in[4];
    float* out = (float*)d_out;

    float* Qt   = (float*)d_ws;                       // 16 KB
    float* D    = (float*)((char*)d_ws + 16384);      // 256 B
    float* A_ws = (float*)((char*)d_ws + 32768);      // 1 MB

    hmm_setup<<<1, 64, 0, stream>>>(base, init, Qt, D);
    hmm_scan<<<BB, 64, 0, stream>>>(obs, means, logvars, Qt, D, A_ws, out);
    hmm_post<<<2048, 256, 0, stream>>>(out, A_ws);
}

// Round 5
// 525.418 us; speedup vs baseline: 1.8333x; 1.3353x over previous
//
#include <hip/hip_runtime.h>
#include <math.h>

#define BB 128
#define SS 2048
#define HH 64
#define CC 4
#define EPSQ 1e-10f
#define NT ((size_t)BB * SS * HH)

typedef float f2 __attribute__((ext_vector_type(2)));
typedef float f4 __attribute__((ext_vector_type(4)));

// ---- ws layout ----
// 0      : Qt[64][64]   Qt[j][i] = softmax(base)[i][j] + EPS   (16 KB)
// 16384  : D[64]        softmax(init)+EPS                      (256 B)

__global__ __launch_bounds__(64) void hmm_setup(const float* __restrict__ base,
                                                const float* __restrict__ init,
                                                float* __restrict__ Qt,
                                                float* __restrict__ D) {
    const int i = threadIdx.x;  // 0..63
    // row-softmax of base_transition_logits, stored TRANSPOSED (+EPS)
    float mx = -INFINITY;
    for (int k = 0; k < HH; ++k) mx = fmaxf(mx, base[i * HH + k]);
    float z = 0.f;
    for (int k = 0; k < HH; ++k) z += expf(base[i * HH + k] - mx);
    float invz = 1.f / z;
    for (int k = 0; k < HH; ++k) Qt[k * HH + i] = expf(base[i * HH + k] - mx) * invz + EPSQ;
    // init distribution
    float x = init[i];
    float m2 = x;
    for (int d = 1; d < 64; d <<= 1) m2 = fmaxf(m2, __shfl_xor(m2, d, 64));
    float e = expf(x - m2);
    float zz = e;
    for (int d = 1; d < 64; d <<= 1) zz += __shfl_xor(zz, d, 64);
    D[i] = e / zz + EPSQ;
}

// em(x) for state j: c0 + sum_c (a_c + q_c*x_c)*x_c
__device__ __forceinline__ float emv(const f4 x, const f4 a, const f4 q, float c0) {
    float em = c0;
    em = fmaf(fmaf(q.x, x.x, a.x), x.x, em);
    em = fmaf(fmaf(q.y, x.y, a.y), x.y, em);
    em = fmaf(fmaf(q.z, x.z, a.z), x.z, em);
    em = fmaf(fmaf(q.w, x.w, a.w), x.w, em);
    return em;
}

#define PK_MUL(d, a, b) asm("v_pk_mul_f32 %0, %1, %2" : "=v"(d) : "v"(a), "v"(b))
#define PK_FMA(d, a, b) asm("v_pk_fma_f32 %0, %1, %2, %0" : "+v"(d) : "v"(a), "v"(b))
#define PK_ADD(d, a, b) asm("v_pk_add_f32 %0, %1, %2" : "=v"(d) : "v"(a), "v"(b))

// One wave per batch, lane j owns U[j]. Broadcast of U: lane j writes u to LDS
// (ds_write_b32), all lanes read it back as 16 uniform-address ds_read_b128
// (broadcast, conflict-free), consumed by 32 v_pk_fma_f32 (2 FMA/inst).
//   U_t[j] = (sum_i Qt[j][i] * U_{t-1}[i]) * g_t * E_t[j]
// g_t = rcp(U_{t-1}[0]) and E_t = exp(em_t) are produced at the END of step
// t-1 (off the critical path). alpha[t][j] = A_t + log(U_t[j]) is stored
// DIRECTLY (log is store-path only, not loop-carried) -> no post-kernel.
template <int P>
__device__ __forceinline__ void hmm_step(int t, int j, float& u, float& gE, float& gcur,
                                         float& A, const f2 (&qr)[32],
                                         float (&Ubuf)[2][HH], const f4* OBS,
                                         const f4 ea, const f4 eq, float ec,
                                         float* __restrict__ alpha_b) {
    Ubuf[P][j] = u;  // ds_write_b32; DS pipe is in-order within a wave
    // A_t = A_{t-1} - log(g_t): uniform, independent of this step's dot
    A -= __logf(gcur);

    const f4* Up = (const f4*)Ubuf[P];
    f2 acc0, acc1, acc2, acc3;
    {
        f4 v = Up[0];
        f2 lo = __builtin_shufflevector(v, v, 0, 1);
        f2 hi = __builtin_shufflevector(v, v, 2, 3);
        PK_MUL(acc0, qr[0], lo);
        PK_MUL(acc1, qr[1], hi);
    }
    {
        f4 v = Up[1];
        f2 lo = __builtin_shufflevector(v, v, 0, 1);
        f2 hi = __builtin_shufflevector(v, v, 2, 3);
        PK_MUL(acc2, qr[2], lo);
        PK_MUL(acc3, qr[3], hi);
    }
#pragma unroll
    for (int k = 2; k < 16; ++k) {
        f4 v = Up[k];
        f2 lo = __builtin_shufflevector(v, v, 0, 1);
        f2 hi = __builtin_shufflevector(v, v, 2, 3);
        if (k & 1) {
            PK_FMA(acc2, qr[2 * k], lo);
            PK_FMA(acc3, qr[2 * k + 1], hi);
        } else {
            PK_FMA(acc0, qr[2 * k], lo);
            PK_FMA(acc1, qr[2 * k + 1], hi);
        }
    }
    // prefetch next obs (uniform LDS read; consumer is late)
    const int tn = (t < SS - 1) ? t + 1 : SS - 1;
    const f4 xn = OBS[tn];

    f2 sa, sb, s2;
    PK_ADD(sa, acc0, acc1);
    PK_ADD(sb, acc2, acc3);
    PK_ADD(s2, sa, sb);
    const float s = s2.x + s2.y;
    const float un = s * gE;  // gE ready since end of step t-1

    // alpha store: off the loop-carried path
    alpha_b[(size_t)t * HH + j] = A + __logf(un);

    // next step's scale & emission
    gcur = __builtin_amdgcn_rcpf(__int_as_float(
        __builtin_amdgcn_readfirstlane(__float_as_int(un))));
    gE = gcur * __expf(emv(xn, ea, eq, ec));
    u = un;
}

__global__ __launch_bounds__(64, 1) void hmm_scan(const float* __restrict__ obs,
                                                  const float* __restrict__ means,
                                                  const float* __restrict__ logvars,
                                                  const float* __restrict__ Qt,
                                                  const float* __restrict__ D,
                                                  float* __restrict__ out) {
    const int b = blockIdx.x;
    const int j = threadIdx.x;  // 0..63 = state
    __shared__ f4 OBS[SS];        // 32 KB: whole obs sequence for this batch
    __shared__ float Ubuf[2][HH]; // 512 B

    // stage obs (coalesced b128; single wave => no barrier)
    const f4* obs4 = (const f4*)obs + (size_t)b * SS;
#pragma unroll 8
    for (int t = j; t < SS; t += 64) OBS[t] = obs4[t];

    // transition column j (row of Qt) into 32 packed f2 (64 VGPRs)
    f2 qr[32];
    const f4* qrow = (const f4*)(Qt + (size_t)j * HH);
#pragma unroll
    for (int k = 0; k < 16; ++k) {
        f4 v = qrow[k];
        qr[2 * k]     = __builtin_shufflevector(v, v, 0, 1);
        qr[2 * k + 1] = __builtin_shufflevector(v, v, 2, 3);
    }

    // emission constants for state j
    const f4 mu = ((const f4*)means)[j];
    const f4 lv = ((const f4*)logvars)[j];
    f4 ea, eq;
    float ec = 0.f;
    {
        float v0 = __expf(lv.x) + 1e-6f, v1 = __expf(lv.y) + 1e-6f;
        float v2 = __expf(lv.z) + 1e-6f, v3 = __expf(lv.w) + 1e-6f;
        float i0 = 1.f / v0, i1 = 1.f / v1, i2 = 1.f / v2, i3 = 1.f / v3;
        ea.x = mu.x * i0; ea.y = mu.y * i1; ea.z = mu.z * i2; ea.w = mu.w * i3;
        eq.x = -0.5f * i0; eq.y = -0.5f * i1; eq.z = -0.5f * i2; eq.w = -0.5f * i3;
        ec += logf(6.2831853071795864f * v0) + mu.x * mu.x * i0;
        ec += logf(6.2831853071795864f * v1) + mu.y * mu.y * i1;
        ec += logf(6.2831853071795864f * v2) + mu.z * mu.z * i2;
        ec += logf(6.2831853071795864f * v3) + mu.w * mu.w * i3;
        ec = -0.5f * ec;
    }

    float* alpha_b = out + (size_t)b * SS * HH;

    // t = 0
    float u = D[j] * __expf(emv(OBS[0], ea, eq, ec));
    alpha_b[j] = __logf(u);  // A_0 = 0
    float A = 0.f;
    float gcur = __builtin_amdgcn_rcpf(__int_as_float(
        __builtin_amdgcn_readfirstlane(__float_as_int(u))));
    float gE = gcur * __expf(emv(OBS[1], ea, eq, ec));

    // t = 1..2046 in pairs (alternating LDS parity), then the final odd step
#pragma unroll 4
    for (int t = 1; t + 1 < SS; t += 2) {
        hmm_step<1>(t, j, u, gE, gcur, A, qr, Ubuf, OBS, ea, eq, ec, alpha_b);
        hmm_step<0>(t + 1, j, u, gE, gcur, A, qr, Ubuf, OBS, ea, eq, ec, alpha_b);
    }
    hmm_step<1>(SS - 1, j, u, gE, gcur, A, qr, Ubuf, OBS, ea, eq, ec, alpha_b);

    // log-likelihood: ll[b] = A_{S-1} + log(sum_j U_{S-1}[j])
    float ssum = u;
    for (int d = 1; d < 64; d <<= 1) ssum += __shfl_xor(ssum, d, 64);
    if (j == 0) out[NT + b] = A + __logf(ssum);
}

extern "C" void kernel_launch(void* const* d_in, const int* in_sizes, int n_in,
                              void* d_out, int out_size, void* d_ws, size_t ws_size,
                              hipStream_t stream) {
    (void)in_sizes; (void)n_in; (void)out_size; (void)ws_size;
    const float* obs     = (const float*)d_in[0];
    const float* base    = (const float*)d_in[1];
    const float* init    = (const float*)d_in[2];
    const float* means   = (const float*)d_in[3];
    const float* logvars = (const float*)d_in[4];
    float* out = (float*)d_out;

    float* Qt = (float*)d_ws;                   // 16 KB
    float* D  = (float*)((char*)d_ws + 16384);  // 256 B

    hmm_setup<<<1, 64, 0, stream>>>(base, init, Qt, D);
    hmm_scan<<<BB, 64, 0, stream>>>(obs, means, logvars, Qt, D, out);
}